// Round 1
// baseline (249.929 us; speedup 1.0000x reference)
//
#include <hip/hip_runtime.h>
#include <hip/hip_bf16.h>
#include <stdint.h>

// Attention_65214783422545: B=4, S=1024, D=1024, H=16, dk=64
// outputs: attn_w [4,16,1024,1024] fp32 then y [4,1024,1024] fp32
//
// Workspace layout (needs 48 MB):
//   0   : xb   bf16 [4096][1024]            8 MB
//   8M  : wqb  bf16 [1024][1024]            2 MB
//   10M : wkb                                2 MB
//   12M : wvb                                2 MB
//   14M : wob                                2 MB
//   16M : qb   bf16 [64][1024][64] (scaled) 8 MB
//   24M : kb   bf16 [64][1024][64]          8 MB
//   32M : vTb  bf16 [64][64][1024]          8 MB
//   40M : yh   bf16 [4096][1024]            8 MB

typedef short short8 __attribute__((ext_vector_type(8)));
typedef short short4v __attribute__((ext_vector_type(4)));
typedef float f32x4 __attribute__((ext_vector_type(4)));

__device__ __forceinline__ short f2bf(float f) {
    union { __hip_bfloat16 h; short s; } u;
    u.h = __float2bfloat16(f);
    return u.s;
}

#define GLD16(g, l) __builtin_amdgcn_global_load_lds( \
    (const __attribute__((address_space(1))) void*)(g), \
    (__attribute__((address_space(3))) void*)(l), 16, 0, 0)

// ---------------- cast fp32 -> bf16 (vectorized) ----------------
__global__ __launch_bounds__(256) void cast_kernel(const float* __restrict__ in,
                                                   short* __restrict__ out, int n4) {
    for (int i = blockIdx.x * 256 + threadIdx.x; i < n4; i += gridDim.x * 256) {
        float4 v = ((const float4*)in)[i];
        short4v o;
        o[0] = f2bf(v.x); o[1] = f2bf(v.y); o[2] = f2bf(v.z); o[3] = f2bf(v.w);
        ((short4v*)out)[i] = o;
    }
}

// ---------------- GEMM: C[M,N] = A[M,K] @ B[N,K]^T + bias ----------------
// A: bf16 [M=4096][K=1024] row-major, B: bf16 [N=1024][K=1024] row-major (torch W [out,in])
// mode 0: Q -> bf16 [B,H,S,64], val*0.125
// mode 1: K -> bf16 [B,H,S,64]
// mode 2: V -> bf16 [B,H,64,S]  (transposed)
// mode 3: O -> fp32 [M][1024] row-major
__global__ __launch_bounds__(256) void gemm_bt(const short* __restrict__ A,
                                               const short* __restrict__ B,
                                               const float* __restrict__ bias,
                                               void* __restrict__ out, int mode) {
    __shared__ __align__(16) short As[128 * 32];
    __shared__ __align__(16) short Bs[128 * 32];

    const int tid = threadIdx.x;
    const int wave = tid >> 6, lane = tid & 63;
    const int l15 = lane & 15, l4 = lane >> 4;
    const int wm = wave >> 1, wn = wave & 1;
    const int tM = blockIdx.y * 128, tN = blockIdx.x * 128;

    f32x4 acc[4][4] = {};

    for (int kt = 0; kt < 1024; kt += 32) {
        // stage A,B tiles: [128 rows][32 cols] linear in LDS
        #pragma unroll
        for (int rep = 0; rep < 2; ++rep) {
            int slot = (wave * 2 + rep) * 64 + lane;
            int e0 = slot * 8;
            int row = e0 >> 5, col = e0 & 31;
            GLD16(&A[(size_t)(tM + row) * 1024 + kt + col], (char*)As + (size_t)(wave * 2 + rep) * 1024);
            GLD16(&B[(size_t)(tN + row) * 1024 + kt + col], (char*)Bs + (size_t)(wave * 2 + rep) * 1024);
        }
        __syncthreads();

        short8 af[4], bfr[4];
        #pragma unroll
        for (int f = 0; f < 4; ++f) {
            int ra = wm * 64 + f * 16 + l15;
            af[f] = *(const short8*)&As[ra * 32 + l4 * 8];
            int rb = wn * 64 + f * 16 + l15;
            bfr[f] = *(const short8*)&Bs[rb * 32 + l4 * 8];
        }
        #pragma unroll
        for (int i = 0; i < 4; ++i)
            #pragma unroll
            for (int j = 0; j < 4; ++j)
                acc[i][j] = __builtin_amdgcn_mfma_f32_16x16x32_bf16(af[i], bfr[j], acc[i][j], 0, 0, 0);
        __syncthreads();
    }

    // epilogue: C/D layout col=lane&15, row=(lane>>4)*4+v
    #pragma unroll
    for (int i = 0; i < 4; ++i) {
        #pragma unroll
        for (int j = 0; j < 4; ++j) {
            #pragma unroll
            for (int v = 0; v < 4; ++v) {
                int gr = tM + wm * 64 + i * 16 + l4 * 4 + v;  // m index
                int gc = tN + wn * 64 + j * 16 + l15;         // n index
                float val = acc[i][j][v] + bias[gc];
                if (mode == 3) {
                    ((float*)out)[(size_t)gr * 1024 + gc] = val;
                } else {
                    int bb = gr >> 10, s = gr & 1023, h = gc >> 6, dk = gc & 63;
                    if (mode == 2) {
                        ((short*)out)[(((size_t)bb * 16 + h) * 64 + dk) * 1024 + s] = f2bf(val);
                    } else if (mode == 0) {
                        ((short*)out)[(((size_t)bb * 16 + h) * 1024 + s) * 64 + dk] = f2bf(val * 0.125f);
                    } else {
                        ((short*)out)[(((size_t)bb * 16 + h) * 1024 + s) * 64 + dk] = f2bf(val);
                    }
                }
            }
        }
    }
}

// ---------------- fused attention ----------------
// grid: (qb=64, bh=64), block 256 (4 waves)
// Each block: 16 query rows of one (b,h). Scores in registers (wave w owns cols
// [w*256, w*256+256)); cross-wave softmax via LDS; writes attn_w; PV via MFMA
// with wave K-split + LDS partial reduce.
__global__ __launch_bounds__(256) void attn_kernel(const short* __restrict__ q,
                                                   const short* __restrict__ k,
                                                   const short* __restrict__ vT,
                                                   float* __restrict__ attn,
                                                   short* __restrict__ yh) {
    const int qb = blockIdx.x;   // query block 0..63
    const int bh = blockIdx.y;   // b*16+h, 0..63
    const int tid = threadIdx.x;
    const int wave = tid >> 6, lane = tid & 63;
    const int l15 = lane & 15, l4 = lane >> 4;
    const int q0 = qb * 16;
    const int VC = q0 + 16;        // number of valid (computed) columns
    const int c0w = wave * 256;

    __shared__ __align__(16) short pb[16][1024];   // 32 KB  P in bf16
    __shared__ float part[4][16][64];              // 16 KB  PV partials
    __shared__ float red[4][16];                   // reduce buffer

    // Q fragments (A-operand, rows = 16 q-rows, K=64 in 2 chunks of 32)
    short8 qf[2];
    {
        const short* qrow = q + ((size_t)bh * 1024 + q0 + l15) * 64;
        qf[0] = *(const short8*)(qrow + l4 * 8);
        qf[1] = *(const short8*)(qrow + 32 + l4 * 8);
    }

    // ---- scores: sc[cf] holds D[16 rows][16 cols] for cols c0w+cf*16.. ----
    f32x4 sc[16] = {};
    #pragma unroll
    for (int cf = 0; cf < 16; ++cf) {
        int c0 = c0w + cf * 16;
        if (c0 >= VC) break;   // wave-uniform
        const short* krow = k + ((size_t)bh * 1024 + c0 + l15) * 64;
        short8 kf0 = *(const short8*)(krow + l4 * 8);
        short8 kf1 = *(const short8*)(krow + 32 + l4 * 8);
        sc[cf] = __builtin_amdgcn_mfma_f32_16x16x32_bf16(qf[0], kf0, sc[cf], 0, 0, 0);
        sc[cf] = __builtin_amdgcn_mfma_f32_16x16x32_bf16(qf[1], kf1, sc[cf], 0, 0, 0);
    }

    // ---- row max (per j: row r = l4*4+j), masked ----
    float mrow[4];
    #pragma unroll
    for (int j = 0; j < 4; ++j) {
        int r = l4 * 4 + j;
        float m = -1e30f;
        #pragma unroll
        for (int cf = 0; cf < 16; ++cf) {
            int col = c0w + cf * 16 + l15;
            float v = (col <= q0 + r) ? sc[cf][j] : -1e30f;
            m = fmaxf(m, v);
        }
        m = fmaxf(m, __shfl_xor(m, 1));
        m = fmaxf(m, __shfl_xor(m, 2));
        m = fmaxf(m, __shfl_xor(m, 4));
        m = fmaxf(m, __shfl_xor(m, 8));
        mrow[j] = m;
    }
    if (l15 == 0) {
        #pragma unroll
        for (int j = 0; j < 4; ++j) red[wave][l4 * 4 + j] = mrow[j];
    }
    __syncthreads();
    #pragma unroll
    for (int j = 0; j < 4; ++j) {
        int r = l4 * 4 + j;
        mrow[j] = fmaxf(fmaxf(red[0][r], red[1][r]), fmaxf(red[2][r], red[3][r]));
    }
    __syncthreads();

    // ---- exp + row sum ----
    float inv[4];
    float ls[4];
    #pragma unroll
    for (int j = 0; j < 4; ++j) {
        int r = l4 * 4 + j;
        float s = 0.f;
        #pragma unroll
        for (int cf = 0; cf < 16; ++cf) {
            int col = c0w + cf * 16 + l15;
            float e = (col <= q0 + r) ? __expf(sc[cf][j] - mrow[j]) : 0.f;
            sc[cf][j] = e;
            s += e;
        }
        s += __shfl_xor(s, 1);
        s += __shfl_xor(s, 2);
        s += __shfl_xor(s, 4);
        s += __shfl_xor(s, 8);
        ls[j] = s;
    }
    if (l15 == 0) {
        #pragma unroll
        for (int j = 0; j < 4; ++j) red[wave][l4 * 4 + j] = ls[j];
    }
    __syncthreads();
    #pragma unroll
    for (int j = 0; j < 4; ++j) {
        int r = l4 * 4 + j;
        inv[j] = 1.0f / (red[0][r] + red[1][r] + red[2][r] + red[3][r]);
    }

    // ---- normalize, write attn_w, stash bf16 P in LDS ----
    float* arow_base = attn + (size_t)bh * 1048576 + (size_t)q0 * 1024;
    #pragma unroll
    for (int cf = 0; cf < 16; ++cf) {
        #pragma unroll
        for (int j = 0; j < 4; ++j) {
            int r = l4 * 4 + j;
            int col = c0w + cf * 16 + l15;
            float p = sc[cf][j] * inv[j];   // masked entries are exactly 0
            arow_base[(size_t)r * 1024 + col] = p;
            pb[r][col] = f2bf(p);
        }
    }
    __syncthreads();

    // ---- PV: Y[16][64] = P[16][VC] @ V[VC][64]; wave K-split ----
    f32x4 yacc[4] = {};
    const int nch = (VC + 31) >> 5;
    for (int ks = wave; ks < nch; ks += 4) {
        short8 pf = *(const short8*)&pb[l15][ks * 32 + l4 * 8];
        #pragma unroll
        for (int cf = 0; cf < 4; ++cf) {
            const short* vrow = vT + ((size_t)bh * 64 + cf * 16 + l15) * 1024;
            short8 vf = *(const short8*)(vrow + ks * 32 + l4 * 8);
            yacc[cf] = __builtin_amdgcn_mfma_f32_16x16x32_bf16(pf, vf, yacc[cf], 0, 0, 0);
        }
    }
    #pragma unroll
    for (int cf = 0; cf < 4; ++cf)
        #pragma unroll
        for (int j = 0; j < 4; ++j)
            part[wave][l4 * 4 + j][cf * 16 + l15] = yacc[cf][j];
    __syncthreads();

    // ---- cross-wave reduce + write y_heads (bf16, [4096][1024]) ----
    const int b = bh >> 4, h = bh & 15;
    #pragma unroll
    for (int kk = 0; kk < 4; ++kk) {
        int o = tid + kk * 256;
        int r = o >> 6, c = o & 63;
        float s = part[0][r][c] + part[1][r][c] + part[2][r][c] + part[3][r][c];
        yh[((size_t)b * 1024 + q0 + r) * 1024 + h * 64 + c] = f2bf(s);
    }
}

extern "C" void kernel_launch(void* const* d_in, const int* in_sizes, int n_in,
                              void* d_out, int out_size, void* d_ws, size_t ws_size,
                              hipStream_t stream) {
    const float* x  = (const float*)d_in[0];
    const float* Wq = (const float*)d_in[1];
    const float* bq = (const float*)d_in[2];
    const float* Wk = (const float*)d_in[3];
    const float* bk = (const float*)d_in[4];
    const float* Wv = (const float*)d_in[5];
    const float* bv = (const float*)d_in[6];
    const float* Wo = (const float*)d_in[7];
    const float* bo = (const float*)d_in[8];

    char* ws = (char*)d_ws;
    short* xb  = (short*)(ws + ((size_t)0 << 20));
    short* wqb = (short*)(ws + ((size_t)8 << 20));
    short* wkb = (short*)(ws + ((size_t)10 << 20));
    short* wvb = (short*)(ws + ((size_t)12 << 20));
    short* wob = (short*)(ws + ((size_t)14 << 20));
    short* qbp = (short*)(ws + ((size_t)16 << 20));
    short* kbp = (short*)(ws + ((size_t)24 << 20));
    short* vTb = (short*)(ws + ((size_t)32 << 20));
    short* yh  = (short*)(ws + ((size_t)40 << 20));

    float* attn = (float*)d_out;
    float* yout = attn + (size_t)67108864;

    cast_kernel<<<2048, 256, 0, stream>>>(x, xb, 4194304 / 4);
    cast_kernel<<<1024, 256, 0, stream>>>(Wq, wqb, 1048576 / 4);
    cast_kernel<<<1024, 256, 0, stream>>>(Wk, wkb, 1048576 / 4);
    cast_kernel<<<1024, 256, 0, stream>>>(Wv, wvb, 1048576 / 4);
    cast_kernel<<<1024, 256, 0, stream>>>(Wo, wob, 1048576 / 4);

    dim3 gg(8, 32);
    gemm_bt<<<gg, 256, 0, stream>>>(xb, wqb, bq, qbp, 0);
    gemm_bt<<<gg, 256, 0, stream>>>(xb, wkb, bk, kbp, 1);
    gemm_bt<<<gg, 256, 0, stream>>>(xb, wvb, bv, vTb, 2);

    attn_kernel<<<dim3(64, 64), 256, 0, stream>>>(qbp, kbp, vTb, attn, yh);

    gemm_bt<<<gg, 256, 0, stream>>>(yh, wob, bo, yout, 3);
}